// Round 1
// baseline (341.960 us; speedup 1.0000x reference)
//
#include <hip/hip_runtime.h>
#include <hip/hip_cooperative_groups.h>

namespace cg = cooperative_groups;

// s = sum_{b,i,j} X[b,i] W[i,j] G[b,i/128,j/128]; out = s^2.
// Factor over j:  s = sum_{i,jb} Wsum[i,jb] * H[i,jb],
//   Wsum[i,jb] = sum_{c<128} W[i, jb*128+c]
//   H[i,jb]    = sum_b X[b,i] * G[b, i/128, jb]
//
// R7: single cooperative kernel (was 3 launches). Theory: real GPU work is
// ~11-14 us (W 28.3MB + X 9.4MB + G 2.65MB = 40.4MB HBM ~6.5us; VALU ~1.1us;
// LDS-broadcast dot ~2-6us); measured 89us => ~75us is per-iteration overhead
// (256MiB ws poison fill @44us + ~10us/launch boundary x3). Fusing removes 2
// launch boundaries; G-stage + X loads are phase-1-independent so they issue
// BEFORE the first grid.sync, merging all HBM traffic into one window.
// Phase 2 widened BPW 8->12 so 4608 wave-units -> 3072 waves = 768 blocks
// (co-resident: __launch_bounds__(256,4) guarantees >=1024 blocks).

#define B_DIM 1536
#define DI    1536
#define DO    4608
#define NI    12
#define NJ    36
#define GROW  (NI * NJ)            // 432 floats per G batch-row
#define BPW   12                   // b's per wave in phase 2
#define NBLK  768                  // cooperative grid
#define P2_WAVES (NBLK * 4)        // 3072
#define P1_PER_WAVE 9              // 27648 wave-units / 3072 waves

__global__ __launch_bounds__(256, 4) void fused_kernel(
    const float* __restrict__ X, const float* __restrict__ W,
    const float* __restrict__ G, float* __restrict__ WsumT,
    float* __restrict__ partials, float* __restrict__ out)
{
    __shared__ float gs[BPW * 72];   // 12 b x (2 ib x 36 jb) = 3456 B
    __shared__ float red[4];

    const int t    = threadIdx.x;
    const int w    = t >> 6;
    const int lane = t & 63;
    const int beta = blockIdx.x;
    const int wg   = beta * 4 + w;   // global wave id in [0, 3072)

    // ---- Phase 1: WsumT[jb][i]. Unit g in [0,27648): row i=g/18, chunk
    // p=g%18 covers jb={2p,2p+1} (256 floats). All 9 loads issued first (MLP).
    float4 v[P1_PER_WAVE];
    #pragma unroll
    for (int q = 0; q < P1_PER_WAVE; ++q) {
        int g = wg + q * P2_WAVES;
        int i1 = g / 18, p = g - i1 * 18;
        v[q] = ((const float4*)(W + (size_t)i1 * DO + (size_t)p * 256))[lane];
    }
    #pragma unroll
    for (int q = 0; q < P1_PER_WAVE; ++q) {
        int g = wg + q * P2_WAVES;
        int i1 = g / 18, p = g - i1 * 18;
        float s1 = (v[q].x + v[q].y) + (v[q].z + v[q].w);
        #pragma unroll
        for (int off = 16; off > 0; off >>= 1) s1 += __shfl_xor(s1, off, 64);
        // lanes 0..31 hold jb=2p, lanes 32..63 hold jb=2p+1
        if (lane == 0)  WsumT[(size_t)(2 * p)     * DI + i1] = s1;
        if (lane == 32) WsumT[(size_t)(2 * p + 1) * DI + i1] = s1;
    }

    // ---- Prefetch for phase 2 (independent of phase 1 -> overlaps it).
    // Block beta: b-range brng=beta/6 (b0..b0+11), iblk quad c=beta%6.
    const int brng = beta / 6;
    const int c    = beta - brng * 6;
    const int b0   = brng * BPW;
    const int iblk = 4 * c + w;          // [0,24)
    const int i    = iblk * 64 + lane;   // [0,1536)
    const int d    = w >> 1;             // which staged ib row this wave uses

    // G slice [b0..b0+11] x ib{2c,2c+1} x [0..35]: contiguous 72-float runs.
    for (int e = t; e < BPW * 72; e += 256) {
        int b = e / 72, r = e - b * 72;
        gs[e] = G[(size_t)(b0 + b) * GROW + (size_t)(2 * c) * NJ + r];
    }
    // X[b0..b0+11][i] into registers (coalesced, lane<->i).
    const float* xp = X + (size_t)b0 * DI + i;
    float xv[BPW];
    #pragma unroll
    for (int bb = 0; bb < BPW; ++bb) xv[bb] = xp[(size_t)bb * DI];
    #pragma unroll
    for (int bb = 0; bb < BPW; ++bb) asm("" : "+v"(xv[bb]));  // keep resident

    __threadfence();            // WsumT + LDS stage visible device-wide
    cg::this_grid().sync();     // also acts as __syncthreads for gs[]

    // ---- Phase 2: s += x * dot36(wv, G_row); G via LDS broadcast.
    // Loop-invariant Wsum slice, coalesced: wv[k] = WsumT[k][i] (L2/L3 hot).
    float wv[NJ];
    #pragma unroll
    for (int k = 0; k < NJ; ++k) wv[k] = WsumT[(size_t)k * DI + i];

    float s = 0.f;
    #pragma unroll
    for (int bb = 0; bb < BPW; ++bb) {
        const float4* gp = (const float4*)(gs + bb * 72 + d * 36); // uniform addr
        float d0 = 0.f, d1 = 0.f;
        #pragma unroll
        for (int k4 = 0; k4 < 9; ++k4) {
            float4 gv = gp[k4];                  // ds_read_b128 broadcast
            d0 = fmaf(wv[4 * k4 + 0], gv.x, d0);
            d1 = fmaf(wv[4 * k4 + 1], gv.y, d1);
            d0 = fmaf(wv[4 * k4 + 2], gv.z, d0);
            d1 = fmaf(wv[4 * k4 + 3], gv.w, d1);
        }
        s = fmaf(xv[bb], d0 + d1, s);
    }

    #pragma unroll
    for (int off = 1; off < 64; off <<= 1) s += __shfl_xor(s, off, 64);
    if (lane == 0) red[w] = s;
    __syncthreads();
    if (t == 0)
        partials[beta] = (red[0] + red[1]) + (red[2] + red[3]);

    __threadfence();
    cg::this_grid().sync();

    // ---- Phase 3: block 0 reduces 768 partials, squares.
    if (beta == 0) {
        float ss = 0.f;
        #pragma unroll
        for (int e = 0; e < 3; ++e) ss += partials[t + e * 256];
        #pragma unroll
        for (int off = 1; off < 64; off <<= 1) ss += __shfl_xor(ss, off, 64);
        if (lane == 0) red[w] = ss;
        __syncthreads();
        if (t == 0) {
            float tot = (red[0] + red[1]) + (red[2] + red[3]);
            out[0] = tot * tot;
        }
    }
}

extern "C" void kernel_launch(void* const* d_in, const int* in_sizes, int n_in,
                              void* d_out, int out_size, void* d_ws, size_t ws_size,
                              hipStream_t stream) {
    const float* X = (const float*)d_in[0];  // [1536,1536]
    const float* W = (const float*)d_in[1];  // [1536,4608]
    const float* G = (const float*)d_in[2];  // [1536,12,36]
    float* out = (float*)d_out;

    float* WsumT    = (float*)d_ws;                 // 55296 floats, [36][1536]
    float* partials = WsumT + (size_t)NJ * DI;      // 768 floats

    void* args[] = { (void*)&X, (void*)&W, (void*)&G,
                     (void*)&WsumT, (void*)&partials, (void*)&out };
    hipLaunchCooperativeKernel((const void*)fused_kernel,
                               dim3(NBLK), dim3(256), args, 0, stream);
}

// Round 3
// 94.551 us; speedup vs baseline: 3.6167x; 3.6167x over previous
//
#include <hip/hip_runtime.h>

// s = sum_{b,i,j} X[b,i] W[i,j] G[b,i/128,j/128]; out = s^2.
// Factor over j:  s = sum_{i,jb} Wsum[i,jb] * H[i,jb],
//   Wsum[i,jb] = sum_{c<128} W[i, jb*128+c]          (needs only W)
//   H[i,jb]    = sum_b X[b,i] * G[b, i/128, jb]      (needs only X,G)
//
// R9: R8 structure (concurrent producers in one launch, cross-block comms
// only on kernel boundaries -- R7 showed grid.sync costs ~250us) with the
// write-collision fixed: R8 had threads t and t+128 (b-parities 0/1 of the
// same i) both storing to Hp[bc][k][i]. Now each parity owns its own slice
// Hp[bc*2+bp][k][i] (24 slices, 5.3 MB); phase B sums 24 instead of 12.
//   A: blocks 0..143   : partial-H (block=(ib,bchunk of 128); G slice in
//                        LDS, uniform-addr b128 broadcasts, 36 FMA/b/thread)
//      blocks 144..2447: WsumT[jb][i] (3 float4-units/wave, shfl reduce)
//   B: 216 blocks: s += WsumT[T] * sum_sp Hp[sp*55296+T], block partials.
//   C: 1 block: reduce 216 partials, square.

#define B_DIM 1536
#define DI    1536
#define DO    4608
#define NI    12
#define NJ    36
#define GROW  (NI * NJ)          // 432 floats per G batch-row
#define HGRID (NJ * DI)          // 55296 floats per Hp slice
#define NSP   (NI * 2)           // 24 Hp slices: (bchunk, b-parity)
#define NHB   144                // H blocks: 12 ib x 12 bchunks
#define WUPW  3                  // Wsum units per wave
#define NWW   (27648 / WUPW)     // 9216 W waves
#define NWB   (NWW / 4)          // 2304 W blocks
#define NB_A  (NHB + NWB)        // 2448
#define NB_B  (HGRID / 256)      // 216

// ---- Kernel A: concurrent Wsum (W-stream) + partial-H (X,G-stream) ----
__global__ __launch_bounds__(256) void phaseA(const float* __restrict__ X,
                                              const float* __restrict__ W,
                                              const float* __restrict__ G,
                                              float* __restrict__ WsumT,
                                              float* __restrict__ Hp) {
    __shared__ float gsl[128 * NJ];          // 18 KB: G[b0..b0+127][ib][0..35]
    const int t    = threadIdx.x;
    const int w    = t >> 6;
    const int lane = t & 63;
    const int beta = blockIdx.x;

    if (beta < NHB) {
        // ---- H path: block = (ib, bchunk). Exclusive X,G slices (read once).
        const int ib = beta / NI;
        const int bc = beta - ib * NI;
        const int b0 = bc * 128;
        for (int e = t; e < 128 * NJ; e += 256) {
            int b = e / NJ, r = e - b * NJ;
            gsl[e] = G[(size_t)(b0 + b) * GROW + ib * NJ + r];
        }
        __syncthreads();

        const int il = t & 127;              // i_local
        const int bp = t >> 7;               // b parity (wave-uniform)
        const float* xp = X + (size_t)(b0 + bp) * DI + ib * 128 + il;
        float acc[NJ];
        #pragma unroll
        for (int k = 0; k < NJ; ++k) acc[k] = 0.f;

        #pragma unroll 4
        for (int bl = 0; bl < 64; ++bl) {
            float x = xp[(size_t)bl * 2 * DI];                 // coalesced 256B
            const float4* g4 = (const float4*)(gsl + (2 * bl + bp) * NJ);
            #pragma unroll
            for (int k = 0; k < 9; ++k) {                      // uniform addr:
                float4 g = g4[k];                              // b128 broadcast
                acc[4 * k + 0] = fmaf(x, g.x, acc[4 * k + 0]);
                acc[4 * k + 1] = fmaf(x, g.y, acc[4 * k + 1]);
                acc[4 * k + 2] = fmaf(x, g.z, acc[4 * k + 2]);
                acc[4 * k + 3] = fmaf(x, g.w, acc[4 * k + 3]);
            }
        }
        // Slice per (bchunk, parity): no write collision between t and t+128.
        float* hp = Hp + (size_t)(bc * 2 + bp) * HGRID + ib * 128 + il;
        #pragma unroll
        for (int k = 0; k < NJ; ++k) hp[(size_t)k * DI] = acc[k];
    } else {
        // ---- Wsum path: unit g covers row i, chunk p -> jb {2p, 2p+1}.
        const int wgW = (beta - NHB) * 4 + w;
        float4 v[WUPW];
        int ii[WUPW], pp[WUPW];
        #pragma unroll
        for (int q = 0; q < WUPW; ++q) {
            int g = wgW + q * NWW;
            ii[q] = g / 18;
            pp[q] = g - ii[q] * 18;
            v[q] = ((const float4*)(W + (size_t)ii[q] * DO + pp[q] * 256))[lane];
        }
        #pragma unroll
        for (int q = 0; q < WUPW; ++q) {
            float s1 = (v[q].x + v[q].y) + (v[q].z + v[q].w);
            #pragma unroll
            for (int off = 16; off > 0; off >>= 1) s1 += __shfl_xor(s1, off, 64);
            // lanes 0..31 hold jb=2p, lanes 32..63 hold jb=2p+1
            if (lane == 0)  WsumT[(size_t)(2 * pp[q])     * DI + ii[q]] = s1;
            if (lane == 32) WsumT[(size_t)(2 * pp[q] + 1) * DI + ii[q]] = s1;
        }
    }
}

// ---- Kernel B: dot of Wsum with (sum of 24 Hp slices); 216 partials ----
__global__ __launch_bounds__(256) void phaseB(const float* __restrict__ WsumT,
                                              const float* __restrict__ Hp,
                                              float* __restrict__ partials) {
    __shared__ float red[4];
    const int t = threadIdx.x;
    const size_t T = (size_t)blockIdx.x * 256 + t;   // < 55296, flat [jb][i]
    float h = 0.f;
    #pragma unroll
    for (int sp = 0; sp < NSP; ++sp) h += Hp[(size_t)sp * HGRID + T];
    float s = WsumT[T] * h;
    #pragma unroll
    for (int off = 1; off < 64; off <<= 1) s += __shfl_xor(s, off, 64);
    const int w = t >> 6, lane = t & 63;
    if (lane == 0) red[w] = s;
    __syncthreads();
    if (t == 0)
        partials[blockIdx.x] = (red[0] + red[1]) + (red[2] + red[3]);
}

// ---- Kernel C: final reduce + square (1 block) ----
__global__ __launch_bounds__(256) void phaseC(const float* __restrict__ partials,
                                              float* __restrict__ out) {
    __shared__ float red[4];
    const int t = threadIdx.x;
    float s = (t < NB_B) ? partials[t] : 0.f;
    #pragma unroll
    for (int off = 1; off < 64; off <<= 1) s += __shfl_xor(s, off, 64);
    const int w = t >> 6, lane = t & 63;
    if (lane == 0) red[w] = s;
    __syncthreads();
    if (t == 0) {
        float tot = (red[0] + red[1]) + (red[2] + red[3]);
        out[0] = tot * tot;
    }
}

extern "C" void kernel_launch(void* const* d_in, const int* in_sizes, int n_in,
                              void* d_out, int out_size, void* d_ws, size_t ws_size,
                              hipStream_t stream) {
    const float* X = (const float*)d_in[0];  // [1536,1536]
    const float* W = (const float*)d_in[1];  // [1536,4608]
    const float* G = (const float*)d_in[2];  // [1536,12,36]
    float* out = (float*)d_out;

    float* WsumT    = (float*)d_ws;                  // [36][1536]
    float* Hp       = WsumT + HGRID;                 // [24][36][1536]
    float* partials = Hp + (size_t)NSP * HGRID;      // 216 floats

    phaseA<<<NB_A, 256, 0, stream>>>(X, W, G, WsumT, Hp);
    phaseB<<<NB_B, 256, 0, stream>>>(WsumT, Hp, partials);
    phaseC<<<1, 256, 0, stream>>>(partials, out);
}